// Round 5
// baseline (1056.744 us; speedup 1.0000x reference)
//
#include <hip/hip_runtime.h>
#include <hip/hip_cooperative_groups.h>

namespace cg = cooperative_groups;

#define NN 100000
#define EE 1600000
#define NPART 8                   // dst-space partitions
#define PSZ (NN / NPART)          // 12500 nodes per partition
#define NI4 (EE / 4)              // 400000 int4 records in dst/src
#define SUBW 196                  // dst nodes per sub-bucket (64 per partition)
#define NSB (NPART * 64)          // 512 sub-buckets
#define SCAP 4096                 // records per sub-bucket (exp 3125, +17 sigma)
#define RCAP 8192                 // csr slots per sub-bucket region (exp ~3960)
#define FCHUNKS 128               // edge-list chunks per partition
#define FBLOCKS (NPART * FCHUNKS) // 1024 filter blocks
#define WTBLOCKS 48               // 3 matrices x 16 (32x32) transpose tiles
#define LBCAP 48                  // LDS bin capacity (exp 24.4, +4.7 sigma; overflow ok)

typedef __attribute__((ext_vector_type(8))) short bf16x8;
typedef __attribute__((ext_vector_type(4))) float f32x4;

// bf16 helpers (exact unpack; RN pack)
__device__ inline unsigned int f2bf2(float a, float b) {  // pack (a=low, b=high)
    unsigned int ua = __float_as_uint(a);
    unsigned int ub = __float_as_uint(b);
    ua = (ua + 0x7fffu + ((ua >> 16) & 1u)) >> 16;
    ub = (ub + 0x7fffu + ((ub >> 16) & 1u)) >> 16;
    return ua | (ub << 16);
}
__device__ inline unsigned short f2bf(float a) {
    unsigned int u = __float_as_uint(a);
    return (unsigned short)((u + 0x7fffu + ((u >> 16) & 1u)) >> 16);
}
__device__ inline float2 bf2f2(unsigned int u) {
    return make_float2(__uint_as_float(u << 16), __uint_as_float(u & 0xffff0000u));
}

// ---------------- K1: wt transpose-build (blocks 0-47, coalesced via LDS tile,
// dispatched FIRST so they overlap the filter blocks) + partition-filter with
// LDS binning (blocks 48..48+1023). No per-edge global atomics (round-4 lesson:
// they cost ~17 us on the latency-critical loop). Block 0 zeros hb sentinel.

__global__ __launch_bounds__(256) void fbwt_kernel(const int4* __restrict__ src4,
                                                   const int4* __restrict__ dst4,
                                                   int* __restrict__ gcur2,
                                                   uint2* __restrict__ buckets2,
                                                   const float* __restrict__ W1,
                                                   const float* __restrict__ W2,
                                                   const float* __restrict__ W3,
                                                   unsigned short* __restrict__ wt1,
                                                   unsigned short* __restrict__ wt2,
                                                   unsigned short* __restrict__ wt3,
                                                   unsigned int* __restrict__ hb) {
    __shared__ uint2 bins[64][LBCAP];     // 24 KB
    __shared__ int bcnt[64];
    __shared__ int gbase[64];
    __shared__ float tile[32][33];        // 4.2 KB transpose staging

    if (blockIdx.x < WTBLOCKS) {          // ---- wt-build blocks ----
        const int m = blockIdx.x >> 4;    // matrix 0..2
        const int tl = blockIdx.x & 15;   // 32x32 tile
        const int ti = tl >> 2, tj = tl & 3;   // k-tile, n-tile
        const float* W = m == 0 ? W1 : (m == 1 ? W2 : W3);
        unsigned short* wt = m == 0 ? wt1 : (m == 1 ? wt2 : wt3);
        const int r = threadIdx.x >> 5, c = threadIdx.x & 31;
#pragma unroll
        for (int rr = r; rr < 32; rr += 8)     // coalesced read of W[k][n]
            tile[rr][c] = W[(ti * 32 + rr) * 128 + tj * 32 + c];
        __syncthreads();
#pragma unroll
        for (int rr = r; rr < 32; rr += 8)     // coalesced write of wt[n][k]
            wt[(size_t)(tj * 32 + rr) * 128 + ti * 32 + c] = f2bf(tile[c][rr]);
        if (blockIdx.x == 0 && threadIdx.x < 64) hb[(size_t)NN * 64 + threadIdx.x] = 0;
        return;
    }

    // ---- filter blocks ----
    const int fb = blockIdx.x - WTBLOCKS;
    const int p = fb >> 7;                // partition 0..7
    const int ch = fb & 127;              // chunk 0..127
    if (threadIdx.x < 64) bcnt[threadIdx.x] = 0;
    __syncthreads();
    const int lo = p * PSZ, hi = lo + PSZ;
    const int chunk4 = NI4 / FCHUNKS;     // 3125, exact
    const int a0 = ch * chunk4, a1 = a0 + chunk4;
    for (int i = a0 + threadIdx.x; i < a1; i += 256) {
        int4 d4 = dst4[i];
        bool m0 = (d4.x >= lo && d4.x < hi);
        bool m1 = (d4.y >= lo && d4.y < hi);
        bool m2 = (d4.z >= lo && d4.z < hi);
        bool m3 = (d4.w >= lo && d4.w < hi);
        if (!(m0 | m1 | m2 | m3)) continue;
        int4 s4 = src4[i];
        int ss[4] = {s4.x, s4.y, s4.z, s4.w};
        int dd[4] = {d4.x, d4.y, d4.z, d4.w};
        bool mm[4] = {m0, m1, m2, m3};
#pragma unroll
        for (int k = 0; k < 4; ++k) {
            if (!mm[k]) continue;
            int li = (dd[k] - lo) / SUBW;           // 0..63
            int pos = atomicAdd(&bcnt[li], 1);
            if (pos < LBCAP) {
                bins[li][pos] = make_uint2((unsigned)ss[k], (unsigned)dd[k]);
            } else {                                 // rare overflow: direct append
                int sb = p * 64 + li;
                int gp = atomicAdd(&gcur2[sb], 1);
                buckets2[(size_t)sb * SCAP + gp] = make_uint2((unsigned)ss[k], (unsigned)dd[k]);
            }
        }
    }
    __syncthreads();
    if (threadIdx.x < 64) {
        int cc = min(bcnt[threadIdx.x], LBCAP);
        gbase[threadIdx.x] = atomicAdd(&gcur2[p * 64 + threadIdx.x], cc);
        bcnt[threadIdx.x] = cc;
    }
    __syncthreads();
    for (int b = 0; b < 64; ++b) {
        const int cc = bcnt[b];
        uint2* outp = buckets2 + (size_t)(p * 64 + b) * SCAP + gbase[b];
        for (int i = threadIdx.x; i < cc; i += 256) outp[i] = bins[b][i];
    }
}

// ---------------- K2: per sub-bucket LDS counting-sort into padded csr rows ---

__global__ __launch_bounds__(256) void sort3_kernel(const uint2* __restrict__ buckets2,
                                                    const int* __restrict__ gcur2,
                                                    int* __restrict__ csr,
                                                    int* __restrict__ info,
                                                    float* __restrict__ dinv) {
    __shared__ int hist[256];
    __shared__ int pscan[256];
    __shared__ int lcur[256];
    __shared__ int staged[RCAP];
    const int sb = blockIdx.x;
    const int li = sb & 63;
    const int base_node = (sb >> 6) * PSZ + li * SUBW;
    const int nnodes = min(SUBW, PSZ - li * SUBW);  // 196 (152 for last)
    const int scnt = gcur2[sb];
    const uint2* bk = buckets2 + (size_t)sb * SCAP;
    const int t = threadIdx.x;
    hist[t] = 0;
    __syncthreads();
    for (int i = t; i < scnt; i += 256) atomicAdd(&hist[(int)bk[i].y - base_node], 1);
    __syncthreads();
    const int padded = (t < nnodes) ? ((hist[t] + 7) & ~7) : 0;
    pscan[t] = padded;
    __syncthreads();
    for (int off = 1; off < 256; off <<= 1) {
        int v = (t >= off) ? pscan[t - off] : 0;
        __syncthreads();
        pscan[t] += v;
        __syncthreads();
    }
    const int rstart = pscan[t] - padded;           // exclusive scan
    lcur[t] = rstart;
    __syncthreads();
    const int total = pscan[255];                   // multiple of 8
    for (int i = t; i < total; i += 256) staged[i] = NN;  // sentinel fill
    __syncthreads();
    for (int i = t; i < scnt; i += 256) {
        uint2 r = bk[i];
        int pos = atomicAdd(&lcur[(int)r.y - base_node], 1);
        staged[pos] = (int)r.x;
    }
    __syncthreads();
    int4* co = (int4*)(csr + (size_t)sb * RCAP);
    for (int i = t; i < (total >> 2); i += 256) co[i] = ((const int4*)staged)[i];
    if (t < nnodes) {
        int dg = hist[t];
        info[base_node + t] = ((sb * RCAP + rstart) << 8) | dg;   // rowoff<24b, deg<8b
        dinv[base_node + t] = rsqrtf(1.0f + (float)dg);
    }
}

// ---------------- device bodies (byte-identical round-0 math) ----------------

template <bool F32IN>
__device__ __forceinline__ void gemm_wave(int wave, const void* __restrict__ xin,
                                          const unsigned short* __restrict__ wt,
                                          const float* __restrict__ dinv,
                                          unsigned int* __restrict__ hb) {
    const int m0 = wave * 16;
    const int lane = threadIdx.x & 63;
    const int r = lane & 15;
    const int q = lane >> 4;
    const unsigned short* wrow = wt + (size_t)r * 128 + q * 8;
    f32x4 acc[8] = {};
#pragma unroll
    for (int kc = 0; kc < 4; ++kc) {
        bf16x8 xf;
        if (F32IN) {
            const float* xrow = (const float*)xin + (size_t)(m0 + r) * 128 + q * 8 + kc * 32;
            float4 a = *(const float4*)xrow;
            float4 b = *(const float4*)(xrow + 4);
            unsigned short tmp[8] = {f2bf(a.x), f2bf(a.y), f2bf(a.z), f2bf(a.w),
                                     f2bf(b.x), f2bf(b.y), f2bf(b.z), f2bf(b.w)};
            xf = *(const bf16x8*)tmp;
        } else {
            const unsigned short* xrow =
                (const unsigned short*)xin + (size_t)(m0 + r) * 128 + q * 8 + kc * 32;
            xf = *(const bf16x8*)xrow;
        }
#pragma unroll
        for (int nt = 0; nt < 8; ++nt) {
            bf16x8 wf = *(const bf16x8*)(wrow + (size_t)nt * 16 * 128 + kc * 32);
            acc[nt] = __builtin_amdgcn_mfma_f32_16x16x32_bf16(wf, xf, acc[nt], 0, 0, 0);
        }
    }
    const float dvr = dinv[m0 + r];
    unsigned int* hrow = hb + (size_t)(m0 + r) * 64;  // uint = 2 bf16
#pragma unroll
    for (int nt = 0; nt < 8; ++nt) {
        int n = nt * 16 + q * 4;
        *(uint2*)(hrow + (n >> 1)) =
            make_uint2(f2bf2(acc[nt][0] * dvr, acc[nt][1] * dvr),
                       f2bf2(acc[nt][2] * dvr, acc[nt][3] * dvr));
    }
}

template <bool BF16OUT>
__device__ __forceinline__ void agg_node(int d, const unsigned int* __restrict__ hb,
                                         const int* __restrict__ csr,
                                         const int* __restrict__ info,
                                         const float* __restrict__ dinv,
                                         const float2* __restrict__ bias2,
                                         void* __restrict__ outp) {
    const int j = threadIdx.x & 63;     // lane
    const int ifo = info[d];
    int e = ifo >> 8;
    const int end = e + (((ifo & 255) + 7) & ~7);
    float2 acc = bf2f2(hb[(size_t)d * 64 + j]);   // self term: hs[d]
    for (; e + 16 <= end; e += 16) {
        int4 c0 = *(const int4*)(csr + e);
        int4 c1 = *(const int4*)(csr + e + 4);
        int4 c2 = *(const int4*)(csr + e + 8);
        int4 c3 = *(const int4*)(csr + e + 12);
        unsigned int v0 = hb[(size_t)c0.x * 64 + j];
        unsigned int v1 = hb[(size_t)c0.y * 64 + j];
        unsigned int v2 = hb[(size_t)c0.z * 64 + j];
        unsigned int v3 = hb[(size_t)c0.w * 64 + j];
        unsigned int v4 = hb[(size_t)c1.x * 64 + j];
        unsigned int v5 = hb[(size_t)c1.y * 64 + j];
        unsigned int v6 = hb[(size_t)c1.z * 64 + j];
        unsigned int v7 = hb[(size_t)c1.w * 64 + j];
        unsigned int v8 = hb[(size_t)c2.x * 64 + j];
        unsigned int v9 = hb[(size_t)c2.y * 64 + j];
        unsigned int va = hb[(size_t)c2.z * 64 + j];
        unsigned int vb = hb[(size_t)c2.w * 64 + j];
        unsigned int vc = hb[(size_t)c3.x * 64 + j];
        unsigned int vd = hb[(size_t)c3.y * 64 + j];
        unsigned int ve = hb[(size_t)c3.z * 64 + j];
        unsigned int vf = hb[(size_t)c3.w * 64 + j];
        float2 f0 = bf2f2(v0), f1 = bf2f2(v1), f2 = bf2f2(v2), f3 = bf2f2(v3);
        float2 f4 = bf2f2(v4), f5 = bf2f2(v5), f6 = bf2f2(v6), f7 = bf2f2(v7);
        float2 f8 = bf2f2(v8), f9 = bf2f2(v9), fa = bf2f2(va), fb = bf2f2(vb);
        float2 fc = bf2f2(vc), fd = bf2f2(vd), fe = bf2f2(ve), ff = bf2f2(vf);
        acc.x += ((f0.x + f1.x) + (f2.x + f3.x)) + ((f4.x + f5.x) + (f6.x + f7.x)) +
                 ((f8.x + f9.x) + (fa.x + fb.x)) + ((fc.x + fd.x) + (fe.x + ff.x));
        acc.y += ((f0.y + f1.y) + (f2.y + f3.y)) + ((f4.y + f5.y) + (f6.y + f7.y)) +
                 ((f8.y + f9.y) + (fa.y + fb.y)) + ((fc.y + fd.y) + (fe.y + ff.y));
    }
    if (e < end) {  // one trailing 8-batch
        int4 c0 = *(const int4*)(csr + e);
        int4 c1 = *(const int4*)(csr + e + 4);
        unsigned int v0 = hb[(size_t)c0.x * 64 + j];
        unsigned int v1 = hb[(size_t)c0.y * 64 + j];
        unsigned int v2 = hb[(size_t)c0.z * 64 + j];
        unsigned int v3 = hb[(size_t)c0.w * 64 + j];
        unsigned int v4 = hb[(size_t)c1.x * 64 + j];
        unsigned int v5 = hb[(size_t)c1.y * 64 + j];
        unsigned int v6 = hb[(size_t)c1.z * 64 + j];
        unsigned int v7 = hb[(size_t)c1.w * 64 + j];
        float2 f0 = bf2f2(v0), f1 = bf2f2(v1), f2 = bf2f2(v2), f3 = bf2f2(v3);
        float2 f4 = bf2f2(v4), f5 = bf2f2(v5), f6 = bf2f2(v6), f7 = bf2f2(v7);
        acc.x += ((f0.x + f1.x) + (f2.x + f3.x)) + ((f4.x + f5.x) + (f6.x + f7.x));
        acc.y += ((f0.y + f1.y) + (f2.y + f3.y)) + ((f4.y + f5.y) + (f6.y + f7.y));
    }
    const float dv = dinv[d];
    float2 bb = bias2[j];
    float ox = fmaxf(dv * acc.x + bb.x, 0.0f);
    float oy = fmaxf(dv * acc.y + bb.y, 0.0f);
    if (BF16OUT) {
        ((unsigned int*)outp)[(size_t)d * 64 + j] = f2bf2(ox, oy);
    } else {
        ((float2*)outp)[(size_t)d * 64 + j] = make_float2(ox, oy);
    }
}

// ---------------- K3: whole 3-layer net, one cooperative dispatch ------------
// gemm1|agg1|gemm2|agg2|gemm3|agg3 with grid.sync() between phases. Grid-stride
// everywhere; grid sized by occupancy query (expect 6 blocks/CU = 24 waves/CU,
// matching the aggregate's measured 22.7-wave concurrency). Kills 5 dispatch
// gaps and keeps the gather phase at its proven wave-count.

__global__ __launch_bounds__(256, 6) void net_kernel(const float* __restrict__ x0,
                                                     const unsigned short* __restrict__ wt1,
                                                     const unsigned short* __restrict__ wt2,
                                                     const unsigned short* __restrict__ wt3,
                                                     const float* __restrict__ b1,
                                                     const float* __restrict__ b2,
                                                     const float* __restrict__ b3,
                                                     const int* __restrict__ csr,
                                                     const int* __restrict__ info,
                                                     const float* __restrict__ dinv,
                                                     unsigned int* __restrict__ hb,
                                                     unsigned int* __restrict__ xact,
                                                     float* __restrict__ out) {
    cg::grid_group gg = cg::this_grid();
    const int w = threadIdx.x >> 6;
    const int wstride = gridDim.x * 4;
    // G1: hs = dinv * (x0 @ W1)
    for (int wv = blockIdx.x * 4 + w; wv < NN / 16; wv += wstride)
        gemm_wave<true>(wv, (const void*)x0, wt1, dinv, hb);
    gg.sync();
    // A1
    for (int gi = blockIdx.x; gi < NN / 4; gi += gridDim.x)
        agg_node<true>(gi * 4 + w, hb, csr, info, dinv, (const float2*)b1, (void*)xact);
    gg.sync();
    // G2
    for (int wv = blockIdx.x * 4 + w; wv < NN / 16; wv += wstride)
        gemm_wave<false>(wv, (const void*)xact, wt2, dinv, hb);
    gg.sync();
    // A2
    for (int gi = blockIdx.x; gi < NN / 4; gi += gridDim.x)
        agg_node<true>(gi * 4 + w, hb, csr, info, dinv, (const float2*)b2, (void*)xact);
    gg.sync();
    // G3
    for (int wv = blockIdx.x * 4 + w; wv < NN / 16; wv += wstride)
        gemm_wave<false>(wv, (const void*)xact, wt3, dinv, hb);
    gg.sync();
    // A3 -> fp32 final output
    for (int gi = blockIdx.x; gi < NN / 4; gi += gridDim.x)
        agg_node<false>(gi * 4 + w, hb, csr, info, dinv, (const float2*)b3, (void*)out);
}

// ---------------- launch ----------------

extern "C" void kernel_launch(void* const* d_in, const int* in_sizes, int n_in,
                              void* d_out, int out_size, void* d_ws, size_t ws_size,
                              hipStream_t stream) {
    const float* x0 = (const float*)d_in[0];
    const int* ei = (const int*)d_in[1];   // int32 on device (harness contract)
    const float* W1 = (const float*)d_in[2];
    const float* b1 = (const float*)d_in[3];
    const float* W2 = (const float*)d_in[4];
    const float* b2 = (const float*)d_in[5];
    const float* W3 = (const float*)d_in[6];
    const float* b3 = (const float*)d_in[7];
    float* out = (float*)d_out;

    char* ws = (char*)d_ws;
    size_t off = 0;
    auto alloc = [&](size_t bytes) -> void* {
        off = (off + 511) & ~(size_t)511;
        void* p = ws + off;
        off += bytes;
        return p;
    };
    unsigned int* hb  = (unsigned int*)alloc(((size_t)NN + 1) * 64 * 4);   // 25.6 MB hs (+ zero row)
    int*   csr     = (int*)  alloc((size_t)NSB * RCAP * sizeof(int));      // 16.8 MB
    uint2* buckets2 = (uint2*)alloc((size_t)NSB * SCAP * sizeof(uint2));   // 16.8 MB
    int*   info    = (int*)  alloc((size_t)NN * sizeof(int));
    float* dinv    = (float*)alloc((size_t)NN * sizeof(float));
    int*   gcur2   = (int*)  alloc(NSB * sizeof(int));
    unsigned short* wt1 = (unsigned short*)alloc(128 * 128 * 2);
    unsigned short* wt2 = (unsigned short*)alloc(128 * 128 * 2);
    unsigned short* wt3 = (unsigned short*)alloc(128 * 128 * 2);

    // bf16 activation ping buffer for layers 1-2 lives in d_out's first 25.6 MB
    unsigned int* xact = (unsigned int*)d_out;

    const int4* src4 = (const int4*)ei;          // edge_index[0]
    const int4* dst4 = (const int4*)(ei + EE);   // edge_index[1]

    // graph prep (redone every call: ws is re-poisoned)
    hipMemsetAsync(gcur2, 0, NSB * sizeof(int), stream);
    fbwt_kernel<<<WTBLOCKS + FBLOCKS, 256, 0, stream>>>(src4, dst4, gcur2, buckets2,
                                                        W1, W2, W3, wt1, wt2, wt3, hb);
    sort3_kernel<<<NSB, 256, 0, stream>>>(buckets2, gcur2, csr, info, dinv);

    // whole net in one cooperative dispatch
    int nbm = 0;
    hipOccupancyMaxActiveBlocksPerMultiprocessor(&nbm, net_kernel, 256, 0);
    if (nbm < 1) nbm = 1;
    if (nbm > 8) nbm = 8;
    int netGrid = nbm * 256;                     // 256 CUs on MI355X
    void* nargs[] = {(void*)&x0, (void*)&wt1, (void*)&wt2, (void*)&wt3,
                     (void*)&b1, (void*)&b2, (void*)&b3,
                     (void*)&csr, (void*)&info, (void*)&dinv,
                     (void*)&hb, (void*)&xact, (void*)&out};
    hipLaunchCooperativeKernel(net_kernel, dim3(netGrid), dim3(256), nargs, 0u, stream);
}

// Round 6
// 448.939 us; speedup vs baseline: 2.3539x; 2.3539x over previous
//
#include <hip/hip_runtime.h>

#define NN 100000
#define EE 1600000
#define NPART 8                   // dst-space partitions
#define PSZ (NN / NPART)          // 12500 nodes per partition
#define NI4 (EE / 4)              // 400000 int4 records in dst/src
#define SUBW 196                  // dst nodes per sub-bucket (64 per partition)
#define NSB (NPART * 64)          // 512 sub-buckets
#define SCAP 4096                 // records per sub-bucket (exp 3125, +17 sigma)
#define RCAP 8192                 // csr slots per sub-bucket region (exp ~3960)
#define FCHUNKS 128               // edge-list chunks per partition
#define FBLOCKS (NPART * FCHUNKS) // 1024 filter blocks
#define WTBLOCKS 48               // 3 matrices x 16 (32x32) transpose tiles
#define DEGB 64                   // dedicated degree-count blocks
#define LBCAP 48                  // LDS bin capacity (exp 24.4, +4.7 sigma; overflow ok)

typedef __attribute__((ext_vector_type(8))) short bf16x8;
typedef __attribute__((ext_vector_type(4))) float f32x4;

// bf16 helpers (exact unpack; RN pack)
__device__ inline unsigned int f2bf2(float a, float b) {  // pack (a=low, b=high)
    unsigned int ua = __float_as_uint(a);
    unsigned int ub = __float_as_uint(b);
    ua = (ua + 0x7fffu + ((ua >> 16) & 1u)) >> 16;
    ub = (ub + 0x7fffu + ((ub >> 16) & 1u)) >> 16;
    return ua | (ub << 16);
}
__device__ inline unsigned short f2bf(float a) {
    unsigned int u = __float_as_uint(a);
    return (unsigned short)((u + 0x7fffu + ((u >> 16) & 1u)) >> 16);
}
__device__ inline float2 bf2f2(unsigned int u) {
    return make_float2(__uint_as_float(u << 16), __uint_as_float(u & 0xffff0000u));
}

// ---------------- K1: three independent block families in one dispatch -------
// [0,64):       deg-count blocks — coalesced dst4 stream (L2-shared with the
//               filter family), 4 atomicAdds per int4. Removed from the filter
//               loop (round-4 lesson: inline per-edge atomics cost ~17 us there)
//               but kept in-dispatch so sort3||gemm1 overlap survives.
// [64,112):     wt transpose-convert via LDS tile, coalesced both ways.
//               Block 64 zeros the hb sentinel row.
// [112,1136):   partition-filter + LDS bin into 64 sub-buckets per partition.
//               1024 blocks (round-4 fbwt was starved at 2.25 blocks/CU).

__global__ __launch_bounds__(256) void fbwt_kernel(const int4* __restrict__ src4,
                                                   const int4* __restrict__ dst4,
                                                   int* __restrict__ gcur2,
                                                   uint2* __restrict__ buckets2,
                                                   int* __restrict__ deg,
                                                   const float* __restrict__ W1,
                                                   const float* __restrict__ W2,
                                                   const float* __restrict__ W3,
                                                   unsigned short* __restrict__ wt1,
                                                   unsigned short* __restrict__ wt2,
                                                   unsigned short* __restrict__ wt3,
                                                   unsigned int* __restrict__ hb) {
    __shared__ uint2 bins[64][LBCAP];     // 24 KB
    __shared__ int bcnt[64];
    __shared__ int gbase[64];
    __shared__ float tile[32][33];        // 4.2 KB transpose staging
    const int bx = blockIdx.x;

    if (bx < DEGB) {                      // ---- degree-count blocks ----
        const int a0 = bx * (NI4 / DEGB); // 6250 int4 each, exact
        const int a1 = a0 + (NI4 / DEGB);
        for (int i = a0 + threadIdx.x; i < a1; i += 256) {
            int4 d4 = dst4[i];
            atomicAdd(&deg[d4.x], 1);
            atomicAdd(&deg[d4.y], 1);
            atomicAdd(&deg[d4.z], 1);
            atomicAdd(&deg[d4.w], 1);
        }
        return;
    }

    if (bx < DEGB + WTBLOCKS) {           // ---- wt-build blocks ----
        const int wb = bx - DEGB;
        const int m = wb >> 4;            // matrix 0..2
        const int tl = wb & 15;           // 32x32 tile
        const int ti = tl >> 2, tj = tl & 3;   // k-tile, n-tile
        const float* W = m == 0 ? W1 : (m == 1 ? W2 : W3);
        unsigned short* wt = m == 0 ? wt1 : (m == 1 ? wt2 : wt3);
        const int r = threadIdx.x >> 5, c = threadIdx.x & 31;
#pragma unroll
        for (int rr = r; rr < 32; rr += 8)     // coalesced read of W[k][n]
            tile[rr][c] = W[(ti * 32 + rr) * 128 + tj * 32 + c];
        __syncthreads();
#pragma unroll
        for (int rr = r; rr < 32; rr += 8)     // coalesced write of wt[n][k]
            wt[(size_t)(tj * 32 + rr) * 128 + ti * 32 + c] = f2bf(tile[c][rr]);
        if (wb == 0 && threadIdx.x < 64) hb[(size_t)NN * 64 + threadIdx.x] = 0;
        return;
    }

    // ---- filter blocks ----
    const int fb = bx - DEGB - WTBLOCKS;
    const int p = fb >> 7;                // partition 0..7
    const int ch = fb & 127;              // chunk 0..127
    if (threadIdx.x < 64) bcnt[threadIdx.x] = 0;
    __syncthreads();
    const int lo = p * PSZ, hi = lo + PSZ;
    const int chunk4 = NI4 / FCHUNKS;     // 3125, exact
    const int a0 = ch * chunk4, a1 = a0 + chunk4;
    for (int i = a0 + threadIdx.x; i < a1; i += 256) {
        int4 d4 = dst4[i];
        bool m0 = (d4.x >= lo && d4.x < hi);
        bool m1 = (d4.y >= lo && d4.y < hi);
        bool m2 = (d4.z >= lo && d4.z < hi);
        bool m3 = (d4.w >= lo && d4.w < hi);
        if (!(m0 | m1 | m2 | m3)) continue;
        int4 s4 = src4[i];
        int ss[4] = {s4.x, s4.y, s4.z, s4.w};
        int dd[4] = {d4.x, d4.y, d4.z, d4.w};
        bool mm[4] = {m0, m1, m2, m3};
#pragma unroll
        for (int k = 0; k < 4; ++k) {
            if (!mm[k]) continue;
            int li = (dd[k] - lo) / SUBW;           // 0..63
            int pos = atomicAdd(&bcnt[li], 1);
            if (pos < LBCAP) {
                bins[li][pos] = make_uint2((unsigned)ss[k], (unsigned)dd[k]);
            } else {                                 // rare overflow: direct append
                int sb = p * 64 + li;
                int gp = atomicAdd(&gcur2[sb], 1);
                buckets2[(size_t)sb * SCAP + gp] = make_uint2((unsigned)ss[k], (unsigned)dd[k]);
            }
        }
    }
    __syncthreads();
    if (threadIdx.x < 64) {
        int cc = min(bcnt[threadIdx.x], LBCAP);
        gbase[threadIdx.x] = atomicAdd(&gcur2[p * 64 + threadIdx.x], cc);
        bcnt[threadIdx.x] = cc;
    }
    __syncthreads();
    for (int b = 0; b < 64; ++b) {
        const int cc = bcnt[b];
        uint2* outp = buckets2 + (size_t)(p * 64 + b) * SCAP + gbase[b];
        for (int i = threadIdx.x; i < cc; i += 256) outp[i] = bins[b][i];
    }
}

// ---------------- GEMM body: hs(bf16) = dinv[row] * (x @ W) via MFMA ---------
// 64 rows per wave (4 tiles of 16), W-fragments hoisted ONCE into registers.
// (256,2) -> 256-VGPR cap, no spill (round-5 lesson: never starve MFMA regs).
// dinv derived from deg[] (bitwise-identical rsqrtf(1+deg) to sort3's dinv).

template <bool F32IN>
__device__ __forceinline__ void gemm_body(int wave, const void* __restrict__ xin,
                                          const unsigned short* __restrict__ wt,
                                          const int* __restrict__ deg,
                                          unsigned int* __restrict__ hb) {
    const int base = wave * 64;
    if (base >= NN) return;
    const int lane = threadIdx.x & 63;
    const int r = lane & 15;
    const int q = lane >> 4;
    const unsigned short* wrow = wt + (size_t)r * 128 + q * 8;
    bf16x8 wfr[4][8];
#pragma unroll
    for (int kc = 0; kc < 4; ++kc)
#pragma unroll
        for (int nt = 0; nt < 8; ++nt)
            wfr[kc][nt] = *(const bf16x8*)(wrow + (size_t)nt * 16 * 128 + kc * 32);
#pragma unroll
    for (int tt = 0; tt < 4; ++tt) {
        const int m0 = base + tt * 16;
        if (m0 >= NN) break;
        f32x4 acc[8] = {};
#pragma unroll
        for (int kc = 0; kc < 4; ++kc) {
            bf16x8 xf;
            if (F32IN) {
                const float* xrow = (const float*)xin + (size_t)(m0 + r) * 128 + q * 8 + kc * 32;
                float4 a = *(const float4*)xrow;
                float4 b = *(const float4*)(xrow + 4);
                unsigned short tmp[8] = {f2bf(a.x), f2bf(a.y), f2bf(a.z), f2bf(a.w),
                                         f2bf(b.x), f2bf(b.y), f2bf(b.z), f2bf(b.w)};
                xf = *(const bf16x8*)tmp;
            } else {
                const unsigned short* xrow =
                    (const unsigned short*)xin + (size_t)(m0 + r) * 128 + q * 8 + kc * 32;
                xf = *(const bf16x8*)xrow;
            }
#pragma unroll
            for (int nt = 0; nt < 8; ++nt)
                acc[nt] = __builtin_amdgcn_mfma_f32_16x16x32_bf16(wfr[kc][nt], xf, acc[nt], 0, 0, 0);
        }
        const int orow = m0 + r;
        const float dvr = rsqrtf(1.0f + (float)deg[orow]);
        unsigned int* hrow = hb + (size_t)orow * 64;  // uint = 2 bf16
#pragma unroll
        for (int nt = 0; nt < 8; ++nt) {
            int n = nt * 16 + q * 4;
            *(uint2*)(hrow + (n >> 1)) =
                make_uint2(f2bf2(acc[nt][0] * dvr, acc[nt][1] * dvr),
                           f2bf2(acc[nt][2] * dvr, acc[nt][3] * dvr));
        }
    }
}

// ---------------- K2: sort3 (blocks 0-511) + layer-1 GEMM (blocks 512-902) ---
// Independent families: sort3 builds csr/info/dinv; gemm1 reads x0/wt1/deg
// (complete after K1) and writes hb. gemm1 cost fully hidden under sort3.

__global__ __launch_bounds__(256, 2) void sort3_gemm1_kernel(const uint2* __restrict__ buckets2,
                                                             const int* __restrict__ gcur2,
                                                             int* __restrict__ csr,
                                                             int* __restrict__ info,
                                                             float* __restrict__ dinv,
                                                             const float* __restrict__ x0,
                                                             const unsigned short* __restrict__ wt1,
                                                             const int* __restrict__ deg,
                                                             unsigned int* __restrict__ hb) {
    __shared__ int hist[256];
    __shared__ int pscan[256];
    __shared__ int lcur[256];
    __shared__ int staged[RCAP];
    if (blockIdx.x >= 512) {   // layer-1 GEMM blocks
        const int wave = (blockIdx.x - 512) * 4 + (threadIdx.x >> 6);
        gemm_body<true>(wave, (const void*)x0, wt1, deg, hb);
        return;
    }
    const int sb = blockIdx.x;
    const int li = sb & 63;
    const int base_node = (sb >> 6) * PSZ + li * SUBW;
    const int nnodes = min(SUBW, PSZ - li * SUBW);  // 196 (152 for last)
    const int scnt = gcur2[sb];
    const uint2* bk = buckets2 + (size_t)sb * SCAP;
    const int t = threadIdx.x;
    hist[t] = 0;
    __syncthreads();
    for (int i = t; i < scnt; i += 256) atomicAdd(&hist[(int)bk[i].y - base_node], 1);
    __syncthreads();
    const int padded = (t < nnodes) ? ((hist[t] + 7) & ~7) : 0;
    pscan[t] = padded;
    __syncthreads();
    for (int off = 1; off < 256; off <<= 1) {
        int v = (t >= off) ? pscan[t - off] : 0;
        __syncthreads();
        pscan[t] += v;
        __syncthreads();
    }
    const int rstart = pscan[t] - padded;           // exclusive scan
    lcur[t] = rstart;
    __syncthreads();
    const int total = pscan[255];                   // multiple of 8
    for (int i = t; i < total; i += 256) staged[i] = NN;  // sentinel fill
    __syncthreads();
    for (int i = t; i < scnt; i += 256) {
        uint2 r = bk[i];
        int pos = atomicAdd(&lcur[(int)r.y - base_node], 1);
        staged[pos] = (int)r.x;
    }
    __syncthreads();
    int4* co = (int4*)(csr + (size_t)sb * RCAP);
    for (int i = t; i < (total >> 2); i += 256) co[i] = ((const int4*)staged)[i];
    if (t < nnodes) {
        int dg = hist[t];
        info[base_node + t] = ((sb * RCAP + rstart) << 8) | dg;   // rowoff<24b, deg<8b
        dinv[base_node + t] = rsqrtf(1.0f + (float)dg);
    }
}

// standalone GEMM for layers 2/3
template <bool F32IN>
__global__ __launch_bounds__(256, 2) void gemm_kernel(const void* __restrict__ xin,
                                                      const unsigned short* __restrict__ wt,
                                                      const int* __restrict__ deg,
                                                      unsigned int* __restrict__ hb) {
    const int wave = blockIdx.x * 4 + (threadIdx.x >> 6);
    gemm_body<F32IN>(wave, xin, wt, deg, hb);
}

// ---------------- aggregation: out[d] = relu( dv*(hs[d] + sum_e hs[src_e]) + b )
// Round-0 body (verified 62.6 us @ 3.96 TB/s), now grid-stride at 2048 blocks
// (8 blocks/CU = 100% occupancy cap vs round-0's measured 71%). Homogeneous
// gather work per wave, so persistent waves keep full MLP (round-3's failure
// was mixed gather+MFMA residency, not persistence itself).

template <bool BF16OUT>
__device__ __forceinline__ void agg_node(int d, const unsigned int* __restrict__ hb,
                                         const int* __restrict__ csr,
                                         const int* __restrict__ info,
                                         const float* __restrict__ dinv,
                                         const float2* __restrict__ bias2,
                                         void* __restrict__ outp) {
    const int j = threadIdx.x & 63;     // lane
    const int ifo = info[d];
    int e = ifo >> 8;
    const int end = e + (((ifo & 255) + 7) & ~7);
    float2 acc = bf2f2(hb[(size_t)d * 64 + j]);   // self term: hs[d]
    for (; e + 16 <= end; e += 16) {
        int4 c0 = *(const int4*)(csr + e);
        int4 c1 = *(const int4*)(csr + e + 4);
        int4 c2 = *(const int4*)(csr + e + 8);
        int4 c3 = *(const int4*)(csr + e + 12);
        unsigned int v0 = hb[(size_t)c0.x * 64 + j];
        unsigned int v1 = hb[(size_t)c0.y * 64 + j];
        unsigned int v2 = hb[(size_t)c0.z * 64 + j];
        unsigned int v3 = hb[(size_t)c0.w * 64 + j];
        unsigned int v4 = hb[(size_t)c1.x * 64 + j];
        unsigned int v5 = hb[(size_t)c1.y * 64 + j];
        unsigned int v6 = hb[(size_t)c1.z * 64 + j];
        unsigned int v7 = hb[(size_t)c1.w * 64 + j];
        unsigned int v8 = hb[(size_t)c2.x * 64 + j];
        unsigned int v9 = hb[(size_t)c2.y * 64 + j];
        unsigned int va = hb[(size_t)c2.z * 64 + j];
        unsigned int vb = hb[(size_t)c2.w * 64 + j];
        unsigned int vc = hb[(size_t)c3.x * 64 + j];
        unsigned int vd = hb[(size_t)c3.y * 64 + j];
        unsigned int ve = hb[(size_t)c3.z * 64 + j];
        unsigned int vf = hb[(size_t)c3.w * 64 + j];
        float2 f0 = bf2f2(v0), f1 = bf2f2(v1), f2 = bf2f2(v2), f3 = bf2f2(v3);
        float2 f4 = bf2f2(v4), f5 = bf2f2(v5), f6 = bf2f2(v6), f7 = bf2f2(v7);
        float2 f8 = bf2f2(v8), f9 = bf2f2(v9), fa = bf2f2(va), fb = bf2f2(vb);
        float2 fc = bf2f2(vc), fd = bf2f2(vd), fe = bf2f2(ve), ff = bf2f2(vf);
        acc.x += ((f0.x + f1.x) + (f2.x + f3.x)) + ((f4.x + f5.x) + (f6.x + f7.x)) +
                 ((f8.x + f9.x) + (fa.x + fb.x)) + ((fc.x + fd.x) + (fe.x + ff.x));
        acc.y += ((f0.y + f1.y) + (f2.y + f3.y)) + ((f4.y + f5.y) + (f6.y + f7.y)) +
                 ((f8.y + f9.y) + (fa.y + fb.y)) + ((fc.y + fd.y) + (fe.y + ff.y));
    }
    if (e < end) {  // one trailing 8-batch
        int4 c0 = *(const int4*)(csr + e);
        int4 c1 = *(const int4*)(csr + e + 4);
        unsigned int v0 = hb[(size_t)c0.x * 64 + j];
        unsigned int v1 = hb[(size_t)c0.y * 64 + j];
        unsigned int v2 = hb[(size_t)c0.z * 64 + j];
        unsigned int v3 = hb[(size_t)c0.w * 64 + j];
        unsigned int v4 = hb[(size_t)c1.x * 64 + j];
        unsigned int v5 = hb[(size_t)c1.y * 64 + j];
        unsigned int v6 = hb[(size_t)c1.z * 64 + j];
        unsigned int v7 = hb[(size_t)c1.w * 64 + j];
        float2 f0 = bf2f2(v0), f1 = bf2f2(v1), f2 = bf2f2(v2), f3 = bf2f2(v3);
        float2 f4 = bf2f2(v4), f5 = bf2f2(v5), f6 = bf2f2(v6), f7 = bf2f2(v7);
        acc.x += ((f0.x + f1.x) + (f2.x + f3.x)) + ((f4.x + f5.x) + (f6.x + f7.x));
        acc.y += ((f0.y + f1.y) + (f2.y + f3.y)) + ((f4.y + f5.y) + (f6.y + f7.y));
    }
    const float dv = dinv[d];
    float2 bb = bias2[j];
    float ox = fmaxf(dv * acc.x + bb.x, 0.0f);
    float oy = fmaxf(dv * acc.y + bb.y, 0.0f);
    if (BF16OUT) {
        ((unsigned int*)outp)[(size_t)d * 64 + j] = f2bf2(ox, oy);
    } else {
        ((float2*)outp)[(size_t)d * 64 + j] = make_float2(ox, oy);
    }
}

template <bool BF16OUT>
__global__ __launch_bounds__(256) void aggregate_kernel(const unsigned int* __restrict__ hb,
                                                        const int* __restrict__ csr,
                                                        const int* __restrict__ info,
                                                        const float* __restrict__ dinv,
                                                        const float2* __restrict__ bias2,
                                                        void* __restrict__ outp) {
    const int w = threadIdx.x >> 6;
    const int stride = (int)gridDim.x * 4;
    for (int d = blockIdx.x * 4 + w; d < NN; d += stride)
        agg_node<BF16OUT>(d, hb, csr, info, dinv, bias2, outp);
}

// ---------------- launch ----------------

extern "C" void kernel_launch(void* const* d_in, const int* in_sizes, int n_in,
                              void* d_out, int out_size, void* d_ws, size_t ws_size,
                              hipStream_t stream) {
    const float* x0 = (const float*)d_in[0];
    const int* ei = (const int*)d_in[1];   // int32 on device (harness contract)
    const float* W1 = (const float*)d_in[2];
    const float* b1 = (const float*)d_in[3];
    const float* W2 = (const float*)d_in[4];
    const float* b2 = (const float*)d_in[5];
    const float* W3 = (const float*)d_in[6];
    const float* b3 = (const float*)d_in[7];
    float* out = (float*)d_out;

    char* ws = (char*)d_ws;
    size_t off = 0;
    auto alloc = [&](size_t bytes) -> void* {
        off = (off + 511) & ~(size_t)511;
        void* p = ws + off;
        off += bytes;
        return p;
    };
    unsigned int* hb  = (unsigned int*)alloc(((size_t)NN + 1) * 64 * 4);   // 25.6 MB hs (+ zero row)
    int*   csr     = (int*)  alloc((size_t)NSB * RCAP * sizeof(int));      // 16.8 MB
    uint2* buckets2 = (uint2*)alloc((size_t)NSB * SCAP * sizeof(uint2));   // 16.8 MB
    int*   info    = (int*)  alloc((size_t)NN * sizeof(int));
    float* dinv    = (float*)alloc((size_t)NN * sizeof(float));
    int*   deg     = (int*)  alloc((size_t)NN * sizeof(int));
    int*   gcur2   = (int*)  alloc(NSB * sizeof(int));
    unsigned short* wt1 = (unsigned short*)alloc(128 * 128 * 2);
    unsigned short* wt2 = (unsigned short*)alloc(128 * 128 * 2);
    unsigned short* wt3 = (unsigned short*)alloc(128 * 128 * 2);

    // bf16 activation ping buffer for layers 1-2 lives in d_out's first 25.6 MB
    unsigned int* xact = (unsigned int*)d_out;

    const int4* src4 = (const int4*)ei;          // edge_index[0]
    const int4* dst4 = (const int4*)(ei + EE);   // edge_index[1]

    // graph prep (redone every call: ws is re-poisoned)
    hipMemsetAsync(gcur2, 0, NSB * sizeof(int), stream);
    hipMemsetAsync(deg, 0, (size_t)NN * sizeof(int), stream);
    fbwt_kernel<<<DEGB + WTBLOCKS + FBLOCKS, 256, 0, stream>>>(src4, dst4, gcur2, buckets2, deg,
                                                               W1, W2, W3, wt1, wt2, wt3, hb);
    // sort3 + layer-1 GEMM overlapped in one launch
    sort3_gemm1_kernel<<<903, 256, 0, stream>>>(buckets2, gcur2, csr, info, dinv,
                                                x0, wt1, deg, hb);
    aggregate_kernel<true><<<2048, 256, 0, stream>>>(hb, csr, info, dinv,
                                                     (const float2*)b1, (void*)xact);
    gemm_kernel<false><<<391, 256, 0, stream>>>((const void*)xact, wt2, deg, hb);
    aggregate_kernel<true><<<2048, 256, 0, stream>>>(hb, csr, info, dinv,
                                                     (const float2*)b2, (void*)xact);
    gemm_kernel<false><<<391, 256, 0, stream>>>((const void*)xact, wt3, deg, hb);
    aggregate_kernel<false><<<2048, 256, 0, stream>>>(hb, csr, info, dinv,
                                                      (const float2*)b3, (void*)out);
}